// Round 3
// baseline (700.718 us; speedup 1.0000x reference)
//
#include <hip/hip_runtime.h>

#define NREL 3
#define NB    64          // buckets per push-list (kills same-address atomic serialization)
#define CAP0  131072      // nodes needing h0  (expected ~45K)
#define CAP1  65536       // nodes needing h1  (expected ~15K)
#define CAPE1 262144      // layer-1 relevant edges (expected ~30K)
#define CAPE2 65536       // layer-2 relevant edges (expected ~10K)
#define BC0   (CAP0 / NB)   // 2048
#define BC1   (CAP1 / NB)   // 1024
#define BCE1  (CAPE1 / NB)  // 4096
#define BCE2  (CAPE2 / NB)  // 1024
// ctr layout (256 ints): [0,64)=nodes1, [64,128)=nodes0, [128,192)=elist1, [192,256)=elist2

// Claim node n: winner (CAS -1 -> -2) allocates a bucketed slot and publishes it.
// atomicExch (not plain store) so the publish lands at the same device coherence
// point as competing CASes within this dispatch (cross-XCD L2s not coherent).
__device__ __forceinline__ void claim_node(int n, int* __restrict__ slot,
                                           int* __restrict__ nodes,
                                           int* __restrict__ bctr, int bcap, int bucket) {
    if (atomicCAS(&slot[n], -1, -2) == -1) {
        int p = atomicAdd(&bctr[bucket], 1);
        if (p < bcap) {
            int sl = bucket * bcap + p;
            nodes[sl] = n;                 // read only by later dispatches
            atomicExch(&slot[n], sl);
        }
    }
}

// ---- mark last node of each graph; claim its h1 and h0 slots ----
__global__ void mark_last_k(const int* __restrict__ ptr, int* __restrict__ inv_map,
                            int* __restrict__ slot1, int* __restrict__ slot0,
                            int* __restrict__ nodes1, int* __restrict__ nodes0,
                            int* __restrict__ ctr, int G) {
    int g = blockIdx.x * blockDim.x + threadIdx.x;
    if (g >= G) return;
    int bucket = (g >> 6) & (NB - 1);
    int last = ptr[g + 1] - 1;
    inv_map[last] = g;
    claim_node(last, slot1, nodes1, ctr + 0,  BC1, bucket);
    claim_node(last, slot0, nodes0, ctr + 64, BC0, bucket);
}

// ---- scan edges: edges into last nodes -> elist2 buckets; srcs claim h1+h0 ----
__global__ void edge_pass1_k(const int* __restrict__ src, const int* __restrict__ dst,
                             const int* __restrict__ inv_map, int* __restrict__ slot1,
                             int* __restrict__ slot0, int* __restrict__ nodes1,
                             int* __restrict__ nodes0, int* __restrict__ elist2,
                             int* __restrict__ ctr, int nE) {
    int t = blockIdx.x * blockDim.x + threadIdx.x;
    int bucket = (t >> 6) & (NB - 1);
    int e0 = t * 4;
    if (e0 >= nE) return;
    int d[4];
    int cnt = min(4, nE - e0);
    if (cnt == 4) { int4 v = *(const int4*)(dst + e0); d[0]=v.x; d[1]=v.y; d[2]=v.z; d[3]=v.w; }
    else for (int k = 0; k < cnt; k++) d[k] = dst[e0 + k];
#pragma unroll
    for (int k = 0; k < 4; k++) {
        if (k >= cnt) break;
        if (inv_map[d[k]] >= 0) {
            int p = atomicAdd(&ctr[192 + bucket], 1);
            if (p < BCE2) elist2[bucket * BCE2 + p] = e0 + k;
            int s = src[e0 + k];
            claim_node(s, slot1, nodes1, ctr + 0,  BC1, bucket);
            claim_node(s, slot0, nodes0, ctr + 64, BC0, bucket);
        }
    }
}

// ---- scan edges: edges into need1 -> elist1 buckets, per-(slot,rel) counts, srcs claim h0 ----
__global__ void edge_pass2_k(const int* __restrict__ src, const int* __restrict__ dst,
                             const int* __restrict__ et, const int* __restrict__ slot1,
                             int* __restrict__ slot0, int* __restrict__ nodes0,
                             int* __restrict__ elist1, float* __restrict__ cntc,
                             int* __restrict__ ctr, int nE) {
    int t = blockIdx.x * blockDim.x + threadIdx.x;
    int bucket = (t >> 6) & (NB - 1);
    int e0 = t * 4;
    if (e0 >= nE) return;
    int d[4];
    int cnt = min(4, nE - e0);
    if (cnt == 4) { int4 v = *(const int4*)(dst + e0); d[0]=v.x; d[1]=v.y; d[2]=v.z; d[3]=v.w; }
    else for (int k = 0; k < cnt; k++) d[k] = dst[e0 + k];
#pragma unroll
    for (int k = 0; k < 4; k++) {
        if (k >= cnt) break;
        int s1 = slot1[d[k]];
        if (s1 >= 0) {
            int e = e0 + k;
            int p = atomicAdd(&ctr[128 + bucket], 1);
            if (p < BCE1) elist1[bucket * BCE1 + p] = e;
            atomicAdd(&cntc[s1 * 4 + et[e]], 1.0f);
            claim_node(src[e], slot0, nodes0, ctr + 64, BC0, bucket);
        }
    }
}

// ---- counts -> reciprocals (mean folded into per-edge scale) ----
__global__ void inv_k(float* __restrict__ cntc, int n) {
    int i = blockIdx.x * blockDim.x + threadIdx.x;
    if (i < n) cntc[i] = 1.0f / fmaxf(cntc[i], 1.0f);
}

// ---- embed + pre-linear + relu for claimed h0 slots ----
__global__ void h0_k(const int* __restrict__ x, const float* __restrict__ se,
                     const float* __restrict__ ce, const float* __restrict__ pw,
                     const float* __restrict__ pb, const int* __restrict__ nodes0,
                     const int* __restrict__ ctr, float* __restrict__ h0c) {
    __shared__ float s_se[128], s_ce[128], s_pw[512], s_pb[32];
    int t = threadIdx.x;
    if (t < 128) { s_se[t] = se[t]; s_ce[t] = ce[t]; }
    if (t < 32)  s_pb[t] = pb[t];
    for (int i = t; i < 512; i += 256) s_pw[i] = pw[i];
    __syncthreads();
    for (int idx = blockIdx.x * blockDim.x + t; idx < CAP0 * 32; idx += gridDim.x * blockDim.x) {
        int p = idx >> 5, f = idx & 31;
        int b = p >> 11, i = p & (BC0 - 1);           // BC0 = 2048
        if (i >= min(ctr[64 + b], BC0)) continue;
        int n = nodes0[p];
        int x0 = x[n * 2], x1 = x[n * 2 + 1];
        float acc = s_pb[f];
#pragma unroll
        for (int k = 0; k < 8; k++) acc += s_se[x0 * 8 + k] * s_pw[k * 32 + f];
#pragma unroll
        for (int k = 0; k < 8; k++) acc += s_ce[x1 * 8 + k] * s_pw[(k + 8) * 32 + f];
        h0c[p * 32 + f] = fmaxf(acc, 0.0f);
    }
}

// ---- layer-1 messages over elist1 buckets: wave per edge, lane = out feature ----
__global__ void msg1_k(const int* __restrict__ src, const int* __restrict__ dst,
                       const int* __restrict__ et, const int* __restrict__ elist1,
                       const int* __restrict__ slot0, const int* __restrict__ slot1,
                       const float* __restrict__ w1r, const float* __restrict__ cinv,
                       const float* __restrict__ h0c, float* __restrict__ agg1,
                       const int* __restrict__ ctr) {
    __shared__ float s_w[NREL * 32 * 64];   // 24 KB
    int t = threadIdx.x;
    for (int i = t; i < NREL * 32 * 64; i += blockDim.x) s_w[i] = w1r[i];
    __syncthreads();
    int f = t & 63;
    int wv  = (blockIdx.x * blockDim.x + t) >> 6;
    int nwv = (gridDim.x * blockDim.x) >> 6;
    for (int j = wv; j < CAPE1; j += nwv) {
        int b = j >> 12, i = j & (BCE1 - 1);          // BCE1 = 4096
        if (i >= min(ctr[128 + b], BCE1)) continue;
        int e = elist1[j];
        int s = src[e], d = dst[e], r = et[e];
        int s0 = slot0[s], s1 = slot1[d];
        if (s0 < 0 || s1 < 0) continue;
        float scale = cinv[s1 * 4 + r];
        const float4* h4 = (const float4*)(h0c + (size_t)s0 * 32);
        float acc = 0.0f;
#pragma unroll
        for (int k4 = 0; k4 < 8; k4++) {
            float4 hv = h4[k4];
            const float* wp = &s_w[r * 2048 + (k4 * 4) * 64 + f];
            acc += hv.x * wp[0] + hv.y * wp[64] + hv.z * wp[128] + hv.w * wp[192];
        }
        atomicAdd(&agg1[(size_t)s1 * 64 + f], acc * scale);
    }
}

// ---- finalize layer 1: h1 = relu(agg1 + h0 @ w_root + b) over claimed h1 slots ----
__global__ void fin1_k(const float* __restrict__ wroot, const float* __restrict__ b,
                       const int* __restrict__ nodes1, const int* __restrict__ slot0,
                       const float* __restrict__ h0c, const float* __restrict__ agg1,
                       float* __restrict__ h1c, const int* __restrict__ ctr) {
    __shared__ float s_wr[32 * 64], s_b[64];
    int t = threadIdx.x;
    for (int i = t; i < 32 * 64; i += blockDim.x) s_wr[i] = wroot[i];
    if (t < 64) s_b[t] = b[t];
    __syncthreads();
    int f = t & 63;
    int wv  = (blockIdx.x * blockDim.x + t) >> 6;
    int nwv = (gridDim.x * blockDim.x) >> 6;
    for (int j = wv; j < CAP1; j += nwv) {
        int b_ = j >> 10, i = j & (BC1 - 1);          // BC1 = 1024
        if (i >= min(ctr[0 + b_], BC1)) continue;
        int n = nodes1[j];
        int s0 = slot0[n];
        if (s0 < 0) continue;
        float acc = s_b[f];
        const float4* h4 = (const float4*)(h0c + (size_t)s0 * 32);
#pragma unroll
        for (int k4 = 0; k4 < 8; k4++) {
            float4 hv = h4[k4];
            const float* wp = &s_wr[(k4 * 4) * 64 + f];
            acc += hv.x * wp[0] + hv.y * wp[64] + hv.z * wp[128] + hv.w * wp[192];
        }
        h1c[(size_t)j * 64 + f] = fmaxf(agg1[(size_t)j * 64 + f] + acc, 0.0f);
    }
}

// ---- layer-2 messages over elist2 buckets into per-graph agg2 ----
__global__ void msg2_k(const int* __restrict__ src, const int* __restrict__ dst,
                       const int* __restrict__ et, const int* __restrict__ elist2,
                       const int* __restrict__ slot1, const int* __restrict__ inv_map,
                       const float* __restrict__ w2r, const float* __restrict__ cinv,
                       const float* __restrict__ h1c, float* __restrict__ agg2,
                       const int* __restrict__ ctr) {
    __shared__ float s_w[NREL * 64 * 64];   // 48 KB
    int t = threadIdx.x;
    for (int i = t; i < NREL * 64 * 64; i += blockDim.x) s_w[i] = w2r[i];
    __syncthreads();
    int f = t & 63;
    int wv  = (blockIdx.x * blockDim.x + t) >> 6;
    int nwv = (gridDim.x * blockDim.x) >> 6;
    for (int j = wv; j < CAPE2; j += nwv) {
        int b = j >> 10, i = j & (BCE2 - 1);          // BCE2 = 1024
        if (i >= min(ctr[192 + b], BCE2)) continue;
        int e = elist2[j];
        int s = src[e], d = dst[e], r = et[e];
        int ss = slot1[s], sd = slot1[d], g = inv_map[d];
        if (ss < 0 || sd < 0 || g < 0) continue;
        float scale = cinv[sd * 4 + r];
        const float4* h4 = (const float4*)(h1c + (size_t)ss * 64);
        float acc = 0.0f;
#pragma unroll
        for (int k4 = 0; k4 < 16; k4++) {
            float4 hv = h4[k4];
            const float* wp = &s_w[r * 4096 + (k4 * 4) * 64 + f];
            acc += hv.x * wp[0] + hv.y * wp[64] + hv.z * wp[128] + hv.w * wp[192];
        }
        atomicAdd(&agg2[(size_t)g * 64 + f], acc * scale);
    }
}

// ---- finalize layer 2 + classifier, fused: wave per graph ----
__global__ void fin2cls_k(const int* __restrict__ ptr, const int* __restrict__ slot1,
                          const float* __restrict__ wroot, const float* __restrict__ b2,
                          const float* __restrict__ cw, const float* __restrict__ cb,
                          const float* __restrict__ h1c, const float* __restrict__ agg2,
                          float* __restrict__ out, int G) {
    __shared__ float s_wr[64 * 64], s_cw[64 * 10], s_cb[10], s_b[64], s_h2[256];
    int t = threadIdx.x;
    for (int i = t; i < 64 * 64; i += blockDim.x) s_wr[i] = wroot[i];
    for (int i = t; i < 640; i += blockDim.x) s_cw[i] = cw[i];
    if (t < 10) s_cb[t] = cb[t];
    if (t < 64) s_b[t] = b2[t];
    __syncthreads();
    int wvl = t >> 6, f = t & 63;
    int g = blockIdx.x * 4 + wvl;
    if (g < G) {
        int last = ptr[g + 1] - 1;
        int s1 = slot1[last];
        float acc = s_b[f];
        if (s1 >= 0) {
            const float4* h4 = (const float4*)(h1c + (size_t)s1 * 64);
#pragma unroll
            for (int k4 = 0; k4 < 16; k4++) {
                float4 hv = h4[k4];
                const float* wp = &s_wr[(k4 * 4) * 64 + f];
                acc += hv.x * wp[0] + hv.y * wp[64] + hv.z * wp[128] + hv.w * wp[192];
            }
        }
        s_h2[wvl * 64 + f] = fmaxf(agg2[(size_t)g * 64 + f] + acc, 0.0f);
    }
    __syncthreads();
    if (g < G && f < 10) {
        float acc = s_cb[f];
#pragma unroll
        for (int k = 0; k < 64; k++) acc += s_h2[wvl * 64 + k] * s_cw[k * 10 + f];
        out[g * 10 + f] = acc;
    }
}

static inline size_t rnd(size_t x) { return (x + 255) & ~(size_t)255; }

extern "C" void kernel_launch(void* const* d_in, const int* in_sizes, int n_in,
                              void* d_out, int out_size, void* d_ws, size_t ws_size,
                              hipStream_t stream) {
    const int*   x    = (const int*)d_in[0];
    const int*   ei   = (const int*)d_in[1];
    const int*   et   = (const int*)d_in[2];
    const int*   ptr  = (const int*)d_in[3];
    const float* se   = (const float*)d_in[4];
    const float* ce   = (const float*)d_in[5];
    const float* pw   = (const float*)d_in[6];
    const float* pb   = (const float*)d_in[7];
    const float* w1r  = (const float*)d_in[8];
    const float* w1rt = (const float*)d_in[9];
    const float* b1   = (const float*)d_in[10];
    const float* w2r  = (const float*)d_in[11];
    const float* w2rt = (const float*)d_in[12];
    const float* b2   = (const float*)d_in[13];
    const float* cw   = (const float*)d_in[14];
    const float* cb   = (const float*)d_in[15];
    float* out = (float*)d_out;

    const int nN = in_sizes[0] / 2;   // 500000
    const int nE = in_sizes[2];       // 1000000
    const int G  = in_sizes[3] - 1;   // 5000

    const int* src = ei;
    const int* dst = ei + nE;

    // ---- workspace layout: [zero region][0xFF region][uninitialized] ----
    char* p = (char*)d_ws;
    size_t off = 0;
    auto take = [&](size_t bytes) { size_t o = off; off += rnd(bytes); return o; };

    int*   ctr    = (int*)  (p + take(256 * sizeof(int)));
    float* cntc   = (float*)(p + take((size_t)CAP1 * 4 * 4));
    float* agg1   = (float*)(p + take((size_t)CAP1 * 64 * 4));
    float* agg2   = (float*)(p + take((size_t)G * 64 * 4));
    size_t zero_bytes = off;
    int*   inv_map = (int*) (p + take((size_t)nN * 4));
    int*   slot1  = (int*)  (p + take((size_t)nN * 4));
    int*   slot0  = (int*)  (p + take((size_t)nN * 4));
    size_t ff_off = zero_bytes, ff_bytes = off - zero_bytes;
    int*   elist1 = (int*)  (p + take((size_t)CAPE1 * 4));
    int*   elist2 = (int*)  (p + take((size_t)CAPE2 * 4));
    int*   nodes1 = (int*)  (p + take((size_t)CAP1 * 4));
    int*   nodes0 = (int*)  (p + take((size_t)CAP0 * 4));
    float* h0c    = (float*)(p + take((size_t)CAP0 * 32 * 4));
    float* h1c    = (float*)(p + take((size_t)CAP1 * 64 * 4));
    // total ~61 MB

    hipMemsetAsync(p, 0, zero_bytes, stream);
    hipMemsetAsync(p + ff_off, 0xFF, ff_bytes, stream);   // inv_map/slot1/slot0 = -1

    int nT = (nE + 3) / 4;
    mark_last_k<<<(G + 255) / 256, 256, 0, stream>>>(ptr, inv_map, slot1, slot0, nodes1, nodes0, ctr, G);
    edge_pass1_k<<<(nT + 255) / 256, 256, 0, stream>>>(src, dst, inv_map, slot1, slot0, nodes1, nodes0, elist2, ctr, nE);
    edge_pass2_k<<<(nT + 255) / 256, 256, 0, stream>>>(src, dst, et, slot1, slot0, nodes0, elist1, cntc, ctr, nE);
    inv_k<<<(CAP1 * 4 + 255) / 256, 256, 0, stream>>>(cntc, CAP1 * 4);
    h0_k<<<1024, 256, 0, stream>>>(x, se, ce, pw, pb, nodes0, ctr, h0c);
    msg1_k<<<1024, 256, 0, stream>>>(src, dst, et, elist1, slot0, slot1, w1r, cntc, h0c, agg1, ctr);
    fin1_k<<<512, 256, 0, stream>>>(w1rt, b1, nodes1, slot0, h0c, agg1, h1c, ctr);
    msg2_k<<<256, 256, 0, stream>>>(src, dst, et, elist2, slot1, inv_map, w2r, cntc, h1c, agg2, ctr);
    fin2cls_k<<<(G + 3) / 4, 256, 0, stream>>>(ptr, slot1, w2rt, b2, cw, cb, h1c, agg2, out, G);
}

// Round 4
// 280.575 us; speedup vs baseline: 2.4974x; 2.4974x over previous
//
#include <hip/hip_runtime.h>

#define NREL 3
#define NB    64            // buckets per push-list
#define CS    16            // ints per bucket counter (64 B line each, no false sharing)
#define CAP0  131072        // nodes needing h0  (expected ~45K)
#define CAP1  65536         // nodes needing h1  (expected ~15K)
#define CAPE1 262144        // layer-1 relevant edges (expected ~30K)
#define CAPE2 65536         // layer-2 relevant edges (expected ~10K)
#define BC0   (CAP0 / NB)   // 2048
#define BC1   (CAP1 / NB)   // 1024
#define BCE1  (CAPE1 / NB)  // 4096
#define BCE2  (CAPE2 / NB)  // 1024
// ctr: 4 lists x 64 buckets x 16 ints. list 0=nodes1, 1=nodes0, 2=elist1, 3=elist2
#define CTR(list, b) ((list) * NB * CS + (b) * CS)

__device__ __forceinline__ int bittest(const unsigned* bm, int n) {
    return (bm[n >> 5] >> (n & 31)) & 1u;
}

// Claim node n: winner (CAS -1 -> -2) allocates a bucketed slot and publishes it.
__device__ __forceinline__ void claim_node(int n, int* __restrict__ slot,
                                           int* __restrict__ nodes,
                                           int* __restrict__ ctr, int list,
                                           int bcap, int bucket) {
    if (atomicCAS(&slot[n], -1, -2) == -1) {
        int p = atomicAdd(&ctr[CTR(list, bucket)], 1);
        if (p < bcap) {
            int sl = bucket * bcap + p;
            nodes[sl] = n;                 // read only by later dispatches
            atomicExch(&slot[n], sl);
        }
    }
}

// ---- per graph: mark last node (bitmaps + inv_map), claim its h1/h0 slots ----
__global__ void mark_last_k(const int* __restrict__ ptr, int* __restrict__ inv_map,
                            unsigned* __restrict__ bitL, unsigned* __restrict__ bitN1,
                            int* __restrict__ slot1, int* __restrict__ slot0,
                            int* __restrict__ nodes1, int* __restrict__ nodes0,
                            int* __restrict__ ctr, int G) {
    int g = blockIdx.x * blockDim.x + threadIdx.x;
    if (g >= G) return;
    int bucket = g & (NB - 1);
    int last = ptr[g + 1] - 1;
    inv_map[last] = g;
    atomicOr(&bitL[last >> 5], 1u << (last & 31));
    atomicOr(&bitN1[last >> 5], 1u << (last & 31));
    claim_node(last, slot1, nodes1, ctr, 0, BC1, bucket);
    claim_node(last, slot0, nodes0, ctr, 1, BC0, bucket);
}

// ---- scan edges: dst is a last node -> elist2; src joins need1 (+h0) ----
__global__ void edge_pass1_k(const int* __restrict__ src, const int* __restrict__ dst,
                             const unsigned* __restrict__ bitL, unsigned* __restrict__ bitN1,
                             int* __restrict__ slot1, int* __restrict__ slot0,
                             int* __restrict__ nodes1, int* __restrict__ nodes0,
                             int* __restrict__ elist2, int* __restrict__ ctr, int nE) {
    int t = blockIdx.x * blockDim.x + threadIdx.x;
    int bucket = (t >> 6) & (NB - 1);
    int e0 = t * 4;
    if (e0 >= nE) return;
    int d[4];
    int cnt = min(4, nE - e0);
    if (cnt == 4) { int4 v = *(const int4*)(dst + e0); d[0]=v.x; d[1]=v.y; d[2]=v.z; d[3]=v.w; }
    else for (int k = 0; k < cnt; k++) d[k] = dst[e0 + k];
#pragma unroll
    for (int k = 0; k < 4; k++) {
        if (k >= cnt) break;
        if (bittest(bitL, d[k])) {
            int e = e0 + k;
            int p = atomicAdd(&ctr[CTR(3, bucket)], 1);
            if (p < BCE2) elist2[bucket * BCE2 + p] = e;
            int s = src[e];
            atomicOr(&bitN1[s >> 5], 1u << (s & 31));
            claim_node(s, slot1, nodes1, ctr, 0, BC1, bucket);
            claim_node(s, slot0, nodes0, ctr, 1, BC0, bucket);
        }
    }
}

// ---- scan edges: dst in need1 -> elist1 + per-(slot,rel) counts; src joins h0 set ----
__global__ void edge_pass2_k(const int* __restrict__ src, const int* __restrict__ dst,
                             const int* __restrict__ et, const unsigned* __restrict__ bitN1,
                             const int* __restrict__ slot1, int* __restrict__ slot0,
                             int* __restrict__ nodes0, int* __restrict__ elist1,
                             float* __restrict__ cntc, int* __restrict__ ctr, int nE) {
    int t = blockIdx.x * blockDim.x + threadIdx.x;
    int bucket = (t >> 6) & (NB - 1);
    int e0 = t * 4;
    if (e0 >= nE) return;
    int d[4];
    int cnt = min(4, nE - e0);
    if (cnt == 4) { int4 v = *(const int4*)(dst + e0); d[0]=v.x; d[1]=v.y; d[2]=v.z; d[3]=v.w; }
    else for (int k = 0; k < cnt; k++) d[k] = dst[e0 + k];
#pragma unroll
    for (int k = 0; k < 4; k++) {
        if (k >= cnt) break;
        if (bittest(bitN1, d[k])) {
            int e = e0 + k;
            int s1 = slot1[d[k]];                 // hit path only (~3% of edges)
            if (s1 >= 0) {
                int p = atomicAdd(&ctr[CTR(2, bucket)], 1);
                if (p < BCE1) elist1[bucket * BCE1 + p] = e;
                atomicAdd(&cntc[s1 * 4 + et[e]], 1.0f);
                claim_node(src[e], slot0, nodes0, ctr, 1, BC0, bucket);
            }
        }
    }
}

// ---- counts -> reciprocals (mean folded into per-edge scale) ----
__global__ void inv_k(float* __restrict__ cntc, int n) {
    int i = blockIdx.x * blockDim.x + threadIdx.x;
    if (i < n) cntc[i] = 1.0f / fmaxf(cntc[i], 1.0f);
}

// ---- embed + pre-linear + relu for claimed h0 slots (exact per-bucket counts) ----
__global__ void h0_k(const int* __restrict__ x, const float* __restrict__ se,
                     const float* __restrict__ ce, const float* __restrict__ pw,
                     const float* __restrict__ pb, const int* __restrict__ nodes0,
                     const int* __restrict__ ctr, float* __restrict__ h0c) {
    __shared__ float s_se[128], s_ce[128], s_pw[512], s_pb[32];
    int t = threadIdx.x;
    if (t < 128) { s_se[t] = se[t]; s_ce[t] = ce[t]; }
    if (t < 32)  s_pb[t] = pb[t];
    for (int i = t; i < 512; i += 256) s_pw[i] = pw[i];
    __syncthreads();
    int lane = t & 63, f = lane & 31;
    int wv  = (blockIdx.x * blockDim.x + t) >> 6;
    int nwv = (gridDim.x * blockDim.x) >> 6;
    int b = wv & (NB - 1);
    int cb = min(ctr[CTR(1, b)], BC0);
    int step = (nwv >> 6) * 2;
    for (int i = (wv >> 6) * 2 + (lane >> 5); i < cb; i += step) {
        int p = b * BC0 + i;
        int n = nodes0[p];
        int x0 = x[n * 2], x1 = x[n * 2 + 1];
        float acc = s_pb[f];
#pragma unroll
        for (int k = 0; k < 8; k++) acc += s_se[x0 * 8 + k] * s_pw[k * 32 + f];
#pragma unroll
        for (int k = 0; k < 8; k++) acc += s_ce[x1 * 8 + k] * s_pw[(k + 8) * 32 + f];
        h0c[p * 32 + f] = fmaxf(acc, 0.0f);
    }
}

// ---- layer-1 messages over elist1 buckets (exact counts): wave/edge, lane=feature ----
__global__ void msg1_k(const int* __restrict__ src, const int* __restrict__ dst,
                       const int* __restrict__ et, const int* __restrict__ elist1,
                       const int* __restrict__ slot0, const int* __restrict__ slot1,
                       const float* __restrict__ w1r, const float* __restrict__ cinv,
                       const float* __restrict__ h0c, float* __restrict__ agg1,
                       const int* __restrict__ ctr) {
    __shared__ float s_w[NREL * 32 * 64];   // 24 KB
    int t = threadIdx.x;
    for (int i = t; i < NREL * 32 * 64; i += blockDim.x) s_w[i] = w1r[i];
    __syncthreads();
    int f = t & 63;
    int wv  = (blockIdx.x * blockDim.x + t) >> 6;
    int nwv = (gridDim.x * blockDim.x) >> 6;
    int b = wv & (NB - 1);
    int cb = min(ctr[CTR(2, b)], BCE1);
    int step = nwv >> 6;
    for (int i = wv >> 6; i < cb; i += step) {
        int e = elist1[b * BCE1 + i];
        int s = src[e], d = dst[e], r = et[e];
        int s0 = slot0[s], s1 = slot1[d];
        if (s0 < 0 || s1 < 0) continue;
        float scale = cinv[s1 * 4 + r];
        const float4* h4 = (const float4*)(h0c + (size_t)s0 * 32);
        float acc = 0.0f;
#pragma unroll
        for (int k4 = 0; k4 < 8; k4++) {
            float4 hv = h4[k4];
            const float* wp = &s_w[r * 2048 + (k4 * 4) * 64 + f];
            acc += hv.x * wp[0] + hv.y * wp[64] + hv.z * wp[128] + hv.w * wp[192];
        }
        atomicAdd(&agg1[(size_t)s1 * 64 + f], acc * scale);
    }
}

// ---- finalize layer 1 over claimed h1 slots (exact counts) ----
__global__ void fin1_k(const float* __restrict__ wroot, const float* __restrict__ b1,
                       const int* __restrict__ nodes1, const int* __restrict__ slot0,
                       const float* __restrict__ h0c, const float* __restrict__ agg1,
                       float* __restrict__ h1c, const int* __restrict__ ctr) {
    __shared__ float s_wr[32 * 64], s_b[64];
    int t = threadIdx.x;
    for (int i = t; i < 32 * 64; i += blockDim.x) s_wr[i] = wroot[i];
    if (t < 64) s_b[t] = b1[t];
    __syncthreads();
    int f = t & 63;
    int wv  = (blockIdx.x * blockDim.x + t) >> 6;
    int nwv = (gridDim.x * blockDim.x) >> 6;
    int b = wv & (NB - 1);
    int cb = min(ctr[CTR(0, b)], BC1);
    int step = nwv >> 6;
    for (int i = wv >> 6; i < cb; i += step) {
        int j = b * BC1 + i;
        int n = nodes1[j];
        int s0 = slot0[n];
        if (s0 < 0) continue;
        float acc = s_b[f];
        const float4* h4 = (const float4*)(h0c + (size_t)s0 * 32);
#pragma unroll
        for (int k4 = 0; k4 < 8; k4++) {
            float4 hv = h4[k4];
            const float* wp = &s_wr[(k4 * 4) * 64 + f];
            acc += hv.x * wp[0] + hv.y * wp[64] + hv.z * wp[128] + hv.w * wp[192];
        }
        h1c[(size_t)j * 64 + f] = fmaxf(agg1[(size_t)j * 64 + f] + acc, 0.0f);
    }
}

// ---- layer-2 messages over elist2 buckets (exact counts) into per-graph agg2 ----
__global__ void msg2_k(const int* __restrict__ src, const int* __restrict__ dst,
                       const int* __restrict__ et, const int* __restrict__ elist2,
                       const int* __restrict__ slot1, const int* __restrict__ inv_map,
                       const float* __restrict__ w2r, const float* __restrict__ cinv,
                       const float* __restrict__ h1c, float* __restrict__ agg2,
                       const int* __restrict__ ctr) {
    __shared__ float s_w[NREL * 64 * 64];   // 48 KB
    int t = threadIdx.x;
    for (int i = t; i < NREL * 64 * 64; i += blockDim.x) s_w[i] = w2r[i];
    __syncthreads();
    int f = t & 63;
    int wv  = (blockIdx.x * blockDim.x + t) >> 6;
    int nwv = (gridDim.x * blockDim.x) >> 6;
    int b = wv & (NB - 1);
    int cb = min(ctr[CTR(3, b)], BCE2);
    int step = nwv >> 6;
    for (int i = wv >> 6; i < cb; i += step) {
        int e = elist2[b * BCE2 + i];
        int s = src[e], d = dst[e], r = et[e];
        int ss = slot1[s], sd = slot1[d], g = inv_map[d];
        if (ss < 0 || sd < 0 || g < 0) continue;
        float scale = cinv[sd * 4 + r];
        const float4* h4 = (const float4*)(h1c + (size_t)ss * 64);
        float acc = 0.0f;
#pragma unroll
        for (int k4 = 0; k4 < 16; k4++) {
            float4 hv = h4[k4];
            const float* wp = &s_w[r * 4096 + (k4 * 4) * 64 + f];
            acc += hv.x * wp[0] + hv.y * wp[64] + hv.z * wp[128] + hv.w * wp[192];
        }
        atomicAdd(&agg2[(size_t)g * 64 + f], acc * scale);
    }
}

// ---- finalize layer 2 + classifier, fused: wave per graph ----
__global__ void fin2cls_k(const int* __restrict__ ptr, const int* __restrict__ slot1,
                          const float* __restrict__ wroot, const float* __restrict__ b2,
                          const float* __restrict__ cw, const float* __restrict__ cb,
                          const float* __restrict__ h1c, const float* __restrict__ agg2,
                          float* __restrict__ out, int G) {
    __shared__ float s_wr[64 * 64], s_cw[64 * 10], s_cb[10], s_b[64], s_h2[256];
    int t = threadIdx.x;
    for (int i = t; i < 64 * 64; i += blockDim.x) s_wr[i] = wroot[i];
    for (int i = t; i < 640; i += blockDim.x) s_cw[i] = cw[i];
    if (t < 10) s_cb[t] = cb[t];
    if (t < 64) s_b[t] = b2[t];
    __syncthreads();
    int wvl = t >> 6, f = t & 63;
    int g = blockIdx.x * 4 + wvl;
    if (g < G) {
        int last = ptr[g + 1] - 1;
        int s1 = slot1[last];
        float acc = s_b[f];
        if (s1 >= 0) {
            const float4* h4 = (const float4*)(h1c + (size_t)s1 * 64);
#pragma unroll
            for (int k4 = 0; k4 < 16; k4++) {
                float4 hv = h4[k4];
                const float* wp = &s_wr[(k4 * 4) * 64 + f];
                acc += hv.x * wp[0] + hv.y * wp[64] + hv.z * wp[128] + hv.w * wp[192];
            }
        }
        s_h2[wvl * 64 + f] = fmaxf(agg2[(size_t)g * 64 + f] + acc, 0.0f);
    }
    __syncthreads();
    if (g < G && f < 10) {
        float acc = s_cb[f];
#pragma unroll
        for (int k = 0; k < 64; k++) acc += s_h2[wvl * 64 + k] * s_cw[k * 10 + f];
        out[g * 10 + f] = acc;
    }
}

static inline size_t rnd(size_t x) { return (x + 255) & ~(size_t)255; }

extern "C" void kernel_launch(void* const* d_in, const int* in_sizes, int n_in,
                              void* d_out, int out_size, void* d_ws, size_t ws_size,
                              hipStream_t stream) {
    const int*   x    = (const int*)d_in[0];
    const int*   ei   = (const int*)d_in[1];
    const int*   et   = (const int*)d_in[2];
    const int*   ptr  = (const int*)d_in[3];
    const float* se   = (const float*)d_in[4];
    const float* ce   = (const float*)d_in[5];
    const float* pw   = (const float*)d_in[6];
    const float* pb   = (const float*)d_in[7];
    const float* w1r  = (const float*)d_in[8];
    const float* w1rt = (const float*)d_in[9];
    const float* b1   = (const float*)d_in[10];
    const float* w2r  = (const float*)d_in[11];
    const float* w2rt = (const float*)d_in[12];
    const float* b2   = (const float*)d_in[13];
    const float* cw   = (const float*)d_in[14];
    const float* cb   = (const float*)d_in[15];
    float* out = (float*)d_out;

    const int nN = in_sizes[0] / 2;   // 500000
    const int nE = in_sizes[2];       // 1000000
    const int G  = in_sizes[3] - 1;   // 5000
    const int nBW = (nN + 31) / 32;   // bitmap words (~15625 -> 62.5 KB)

    const int* src = ei;
    const int* dst = ei + nE;

    // ---- workspace layout: [zero region][0xFF region][uninitialized] ----
    char* p = (char*)d_ws;
    size_t off = 0;
    auto take = [&](size_t bytes) { size_t o = off; off += rnd(bytes); return o; };

    int*      ctr   = (int*)     (p + take(4 * NB * CS * sizeof(int)));   // 16 KB
    unsigned* bitL  = (unsigned*)(p + take((size_t)nBW * 4));
    unsigned* bitN1 = (unsigned*)(p + take((size_t)nBW * 4));
    float*    cntc  = (float*)   (p + take((size_t)CAP1 * 4 * 4));
    float*    agg1  = (float*)   (p + take((size_t)CAP1 * 64 * 4));
    float*    agg2  = (float*)   (p + take((size_t)G * 64 * 4));
    size_t zero_bytes = off;
    int*      inv_map = (int*)   (p + take((size_t)nN * 4));
    int*      slot1 = (int*)     (p + take((size_t)nN * 4));
    int*      slot0 = (int*)     (p + take((size_t)nN * 4));
    size_t ff_off = zero_bytes, ff_bytes = off - zero_bytes;
    int*      elist1 = (int*)    (p + take((size_t)CAPE1 * 4));
    int*      elist2 = (int*)    (p + take((size_t)CAPE2 * 4));
    int*      nodes1 = (int*)    (p + take((size_t)CAP1 * 4));
    int*      nodes0 = (int*)    (p + take((size_t)CAP0 * 4));
    float*    h0c   = (float*)   (p + take((size_t)CAP0 * 32 * 4));
    float*    h1c   = (float*)   (p + take((size_t)CAP1 * 64 * 4));
    // total ~60 MB

    hipMemsetAsync(p, 0, zero_bytes, stream);
    hipMemsetAsync(p + ff_off, 0xFF, ff_bytes, stream);   // inv_map/slot1/slot0 = -1

    int nT = (nE + 3) / 4;
    mark_last_k<<<(G + 255) / 256, 256, 0, stream>>>(ptr, inv_map, bitL, bitN1, slot1, slot0,
                                                     nodes1, nodes0, ctr, G);
    edge_pass1_k<<<(nT + 255) / 256, 256, 0, stream>>>(src, dst, bitL, bitN1, slot1, slot0,
                                                       nodes1, nodes0, elist2, ctr, nE);
    edge_pass2_k<<<(nT + 255) / 256, 256, 0, stream>>>(src, dst, et, bitN1, slot1, slot0,
                                                       nodes0, elist1, cntc, ctr, nE);
    inv_k<<<(CAP1 * 4 + 255) / 256, 256, 0, stream>>>(cntc, CAP1 * 4);
    h0_k<<<256, 256, 0, stream>>>(x, se, ce, pw, pb, nodes0, ctr, h0c);
    msg1_k<<<256, 256, 0, stream>>>(src, dst, et, elist1, slot0, slot1, w1r, cntc, h0c, agg1, ctr);
    fin1_k<<<256, 256, 0, stream>>>(w1rt, b1, nodes1, slot0, h0c, agg1, h1c, ctr);
    msg2_k<<<128, 256, 0, stream>>>(src, dst, et, elist2, slot1, inv_map, w2r, cntc, h1c, agg2, ctr);
    fin2cls_k<<<(G + 3) / 4, 256, 0, stream>>>(ptr, slot1, w2rt, b2, cw, cb, h1c, agg2, out, G);
}